// Round 2
// baseline (5566.890 us; speedup 1.0000x reference)
//
#include <hip/hip_runtime.h>
#include <hip/hip_bf16.h>

#define NB 64      // batch
#define NT 512     // time
#define ND 512     // input dim
#define NH 768     // hidden
#define KTOT 1280  // ND + NH
#define NG 3072    // 4*NH

typedef short bf16x8 __attribute__((ext_vector_type(8)));
typedef float f32x4 __attribute__((ext_vector_type(4)));

__device__ __forceinline__ unsigned short f2b(float f) {
    unsigned int u; __builtin_memcpy(&u, &f, 4);
    u = u + 0x7FFFu + ((u >> 16) & 1u);   // round-to-nearest-even
    return (unsigned short)(u >> 16);
}
__device__ __forceinline__ float sigmoidf_(float x) { return 1.f / (1.f + __expf(-x)); }
__device__ __forceinline__ float tanhf_(float x) { return 2.f / (1.f + __expf(-2.f * x)) - 1.f; }

// -------- W transpose+convert: W[KTOT][NG] f32 -> WT[NG][KTOT] bf16 --------
__global__ __launch_bounds__(256) void transpose_w(const float* __restrict__ W,
                                                   unsigned short* __restrict__ WT) {
    __shared__ float tile[64][65];
    int bx = blockIdx.x % (NG / 64);   // col tile
    int by = blockIdx.x / (NG / 64);   // k tile
    int cb = bx * 64, kb = by * 64;
    int tid = threadIdx.x;
    {
        int r = tid >> 2;               // k row in tile, 0..63
        int coff = (tid & 3) * 16;      // col offset
        const float* src = W + (size_t)(kb + r) * NG + cb + coff;
#pragma unroll
        for (int i = 0; i < 16; i += 4) {
            float4 v = *(const float4*)(src + i);
            tile[coff + i][r] = v.x; tile[coff + i + 1][r] = v.y;
            tile[coff + i + 2][r] = v.z; tile[coff + i + 3][r] = v.w;
        }
    }
    __syncthreads();
    {
        int c = tid >> 2;               // col in tile
        int koff = (tid & 3) * 16;
        bf16x8 o0, o1;
#pragma unroll
        for (int i = 0; i < 8; ++i) {
            o0[i] = (short)f2b(tile[c][koff + i]);
            o1[i] = (short)f2b(tile[c][koff + 8 + i]);
        }
        unsigned short* dst = WT + (size_t)(cb + c) * KTOT + kb + koff;
        *(bf16x8*)dst       = o0;
        *(bf16x8*)(dst + 8) = o1;
    }
}

// ---------------- one LSTM time step, both directions ----------------
// grid: 192 blocks = dir(2) x bgroup(2) x hgroup(48); 256 threads (4 waves)
__global__ __launch_bounds__(256) void lstm_step(
    const float* __restrict__ seq,               // [NB][NT][ND] f32
    const int* __restrict__ seq_len,             // [NB]
    const unsigned short* __restrict__ WT,       // [2][NG][KTOT] bf16 (fw, bw)
    const float* __restrict__ bias_fw,           // [NG] f32
    const float* __restrict__ bias_bw,           // [NG] f32
    float* __restrict__ c_state,                 // [2][NB][NH] f32
    const unsigned short* __restrict__ h_in,     // [2][NB][NH] bf16
    unsigned short* __restrict__ h_out,          // [2][NB][NH] bf16
    float* __restrict__ h_final,                 // [2][NB][NH] f32
    float* __restrict__ out,                     // [NB][NT][2*NH] f32
    int step)
{
    __shared__ unsigned short A[32][648];        // Kc=640 chunk, +8 pad
    __shared__ float gl[4][32][16];              // gates i,j,f,o

    int bid = blockIdx.x;
    int hgroup = bid % 48;
    int bgroup = (bid / 48) & 1;
    int dir = bid / 96;
    int b0 = bgroup * 32;
    int hbase = hgroup * 16;
    int tid = threadIdx.x;
    int lane = tid & 63;
    int wave = tid >> 6;                         // = gate index

    const unsigned short* Wd = WT + (size_t)dir * NG * KTOT;
    const float* bias = dir ? bias_bw : bias_fw;
    const unsigned short* hbuf = h_in + (size_t)dir * NB * NH;

    // per-thread staging source row
    int srow = tid >> 3;                         // 0..31
    int sb = b0 + srow;
    int Ls = seq_len[sb];
    int t_in = dir ? (Ls - 1 - step) : step;
    if (t_in < 0) t_in = 0;
    const float* xrow = seq + ((size_t)sb * NT + t_in) * ND;
    const unsigned short* hrow = hbuf + (size_t)sb * NH;
    int koff0 = (tid & 7) * 8;

    // MFMA fragment indexing
    int r0 = lane & 15;
    int q8 = (lane >> 4) * 8;
    int col = wave * NH + hbase + r0;            // global gate column
    const unsigned short* Bp = Wd + (size_t)col * KTOT + q8;

    float bv = bias[col];
    f32x4 acc0; acc0[0] = bv; acc0[1] = bv; acc0[2] = bv; acc0[3] = bv;
    f32x4 acc1 = acc0;

    for (int chunk = 0; chunk < 2; ++chunk) {
        int kc0 = chunk * 640;
        // stage A[32][640] (concat bf16(x_t), h) into LDS
#pragma unroll
        for (int i = 0; i < 10; ++i) {
            int kl = koff0 + i * 64;
            int kg = kc0 + kl;
            if (kg < ND) {
                float4 v0 = *(const float4*)(xrow + kg);
                float4 v1 = *(const float4*)(xrow + kg + 4);
                bf16x8 o;
                o[0] = (short)f2b(v0.x); o[1] = (short)f2b(v0.y);
                o[2] = (short)f2b(v0.z); o[3] = (short)f2b(v0.w);
                o[4] = (short)f2b(v1.x); o[5] = (short)f2b(v1.y);
                o[6] = (short)f2b(v1.z); o[7] = (short)f2b(v1.w);
                *(bf16x8*)&A[srow][kl] = o;
            } else {
                *(bf16x8*)&A[srow][kl] = *(const bf16x8*)(hrow + (kg - ND));
            }
        }
        __syncthreads();
#pragma unroll
        for (int ks = 0; ks < 20; ++ks) {
            int klocal = ks * 32 + q8;
            bf16x8 a0 = *(const bf16x8*)&A[r0][klocal];
            bf16x8 a1 = *(const bf16x8*)&A[r0 + 16][klocal];
            bf16x8 bf = *(const bf16x8*)(Bp + kc0 + ks * 32);
            acc0 = __builtin_amdgcn_mfma_f32_16x16x32_bf16(a0, bf, acc0, 0, 0, 0);
            acc1 = __builtin_amdgcn_mfma_f32_16x16x32_bf16(a1, bf, acc1, 0, 0, 0);
        }
        __syncthreads();
    }

    // C/D layout: col = lane&15, row = (lane>>4)*4 + reg
    int qq = lane >> 4;
#pragma unroll
    for (int r = 0; r < 4; ++r) {
        gl[wave][qq * 4 + r][r0] = acc0[r];
        gl[wave][16 + qq * 4 + r][r0] = acc1[r];
    }
    __syncthreads();

    // fused elementwise LSTM cell update (512 elements, 2 per thread)
    unsigned short* hob = h_out + (size_t)dir * NB * NH;
#pragma unroll
    for (int e = tid; e < 512; e += 256) {
        int bl = e >> 4, hl = e & 15;
        int bb = b0 + bl;
        int Lb = seq_len[bb];
        int hidx = hbase + hl;
        size_t sidx = ((size_t)dir * NB + bb) * NH + hidx;
        unsigned short hv;
        if (step < Lb) {
            float gi = gl[0][bl][hl];
            float gj = gl[1][bl][hl];
            float gf = gl[2][bl][hl];
            float go = gl[3][bl][hl];
            float c = c_state[sidx];
            float nc = c * sigmoidf_(gf + 1.f) + sigmoidf_(gi) * tanhf_(gj);
            float nh = tanhf_(nc) * sigmoidf_(go);
            c_state[sidx] = nc;
            h_final[sidx] = nh;
            hv = f2b(nh);
            int t_out = dir ? (Lb - 1 - step) : step;
            out[((size_t)bb * NT + t_out) * (2 * NH) + dir * NH + hidx] = nh;
        } else {
            hv = hbuf[(size_t)bb * NH + hidx];
        }
        hob[(size_t)bb * NH + hidx] = hv;
    }
}

// ---------------- final hidden state (f32) -> d_out tail ----------------
__global__ __launch_bounds__(256) void write_state(const float* __restrict__ h_final,
                                                   float* __restrict__ out_state) {
    int i = blockIdx.x * 256 + threadIdx.x;      // over 2*NB*NH
    if (i < 2 * NB * NH) {
        int dir = i / (NB * NH);
        int rem = i - dir * (NB * NH);
        int b = rem / NH, h = rem - (rem / NH) * NH;
        out_state[(size_t)b * (2 * NH) + dir * NH + h] = h_final[i];
    }
}

extern "C" void kernel_launch(void* const* d_in, const int* in_sizes, int n_in,
                              void* d_out, int out_size, void* d_ws, size_t ws_size,
                              hipStream_t stream) {
    const float* seq  = (const float*)d_in[0];
    const int* seq_len = (const int*)d_in[1];
    const float* W_fw = (const float*)d_in[2];
    const float* b_fw = (const float*)d_in[3];
    const float* W_bw = (const float*)d_in[4];
    const float* b_bw = (const float*)d_in[5];
    float* out = (float*)d_out;

    char* ws = (char*)d_ws;
    unsigned short* WT = (unsigned short*)ws;                         // [2][NG][KTOT] bf16
    size_t wt_bytes = (size_t)2 * NG * KTOT * 2;                      // 15,728,640
    float* c_state = (float*)(ws + wt_bytes);                         // [2][NB][NH] f32
    size_t c_bytes = (size_t)2 * NB * NH * 4;                         // 393,216
    unsigned short* h_state = (unsigned short*)(ws + wt_bytes + c_bytes); // [2buf][2][NB][NH] bf16
    size_t hbuf_elems = (size_t)2 * NB * NH;
    size_t h_bytes = 2 * hbuf_elems * 2;                              // 393,216
    float* h_final = (float*)(ws + wt_bytes + c_bytes + h_bytes);     // [2][NB][NH] f32

    // zero outputs (masked positions must be exactly 0) and states
    hipMemsetAsync(out, 0, (size_t)NB * NT * 2 * NH * sizeof(float), stream);
    hipMemsetAsync(c_state, 0, c_bytes + h_bytes + c_bytes, stream);  // c + h bufs + h_final

    transpose_w<<<(KTOT / 64) * (NG / 64), 256, 0, stream>>>(W_fw, WT);
    transpose_w<<<(KTOT / 64) * (NG / 64), 256, 0, stream>>>(W_bw, WT + (size_t)NG * KTOT);

    for (int t = 0; t < NT; ++t) {
        lstm_step<<<192, 256, 0, stream>>>(
            seq, seq_len, WT, b_fw, b_bw, c_state,
            h_state + (size_t)(t & 1) * hbuf_elems,
            h_state + (size_t)((t + 1) & 1) * hbuf_elems,
            h_final, out, t);
    }

    write_state<<<(2 * NB * NH + 255) / 256, 256, 0, stream>>>(
        h_final, out + (size_t)NB * NT * 2 * NH);
}

// Round 3
// 5521.268 us; speedup vs baseline: 1.0083x; 1.0083x over previous
//
#include <hip/hip_runtime.h>
#include <hip/hip_bf16.h>

#define NB 64      // batch
#define NT 512     // time
#define ND 512     // input dim
#define NH 768     // hidden
#define KTOT 1280  // ND + NH
#define NG 3072    // 4*NH

typedef short bf16x8 __attribute__((ext_vector_type(8)));
typedef float f32x4 __attribute__((ext_vector_type(4)));

__device__ __forceinline__ unsigned short f2b(float f) {
    unsigned int u; __builtin_memcpy(&u, &f, 4);
    u = u + 0x7FFFu + ((u >> 16) & 1u);   // round-to-nearest-even
    return (unsigned short)(u >> 16);
}
__device__ __forceinline__ float sigmoidf_(float x) { return 1.f / (1.f + __expf(-x)); }
__device__ __forceinline__ float tanhf_(float x) { return 2.f / (1.f + __expf(-2.f * x)) - 1.f; }

// -------- W transpose+convert: W[KTOT][NG] f32 -> WT[NG][KTOT] bf16 --------
__global__ __launch_bounds__(256) void transpose_w(const float* __restrict__ W,
                                                   unsigned short* __restrict__ WT) {
    __shared__ float tile[64][65];
    int bx = blockIdx.x % (NG / 64);   // col tile
    int by = blockIdx.x / (NG / 64);   // k tile
    int cb = bx * 64, kb = by * 64;
    int tid = threadIdx.x;
    {
        int r = tid >> 2;
        int coff = (tid & 3) * 16;
        const float* src = W + (size_t)(kb + r) * NG + cb + coff;
#pragma unroll
        for (int i = 0; i < 16; i += 4) {
            float4 v = *(const float4*)(src + i);
            tile[coff + i][r] = v.x; tile[coff + i + 1][r] = v.y;
            tile[coff + i + 2][r] = v.z; tile[coff + i + 3][r] = v.w;
        }
    }
    __syncthreads();
    {
        int c = tid >> 2;
        int koff = (tid & 3) * 16;
        bf16x8 o0, o1;
#pragma unroll
        for (int i = 0; i < 8; ++i) {
            o0[i] = (short)f2b(tile[c][koff + i]);
            o1[i] = (short)f2b(tile[c][koff + 8 + i]);
        }
        unsigned short* dst = WT + (size_t)(cb + c) * KTOT + kb + koff;
        *(bf16x8*)dst       = o0;
        *(bf16x8*)(dst + 8) = o1;
    }
}

// -------- x f32 -> bf16 (optional, if ws allows) --------
__global__ __launch_bounds__(256) void convert_x(const float* __restrict__ src,
                                                 unsigned short* __restrict__ dst, int n8) {
    int i = blockIdx.x * 256 + threadIdx.x;
    if (i < n8) {
        const float4* s = (const float4*)(src + (size_t)i * 8);
        float4 v0 = s[0], v1 = s[1];
        bf16x8 o;
        o[0] = (short)f2b(v0.x); o[1] = (short)f2b(v0.y);
        o[2] = (short)f2b(v0.z); o[3] = (short)f2b(v0.w);
        o[4] = (short)f2b(v1.x); o[5] = (short)f2b(v1.y);
        o[6] = (short)f2b(v1.z); o[7] = (short)f2b(v1.w);
        *(bf16x8*)(dst + (size_t)i * 8) = o;
    }
}

// ---------------- persistent bidirectional LSTM ----------------
// 192 blocks = dir(2) x bgroup(2) x hgroup(48); 256 threads; 1 block/CU (149KB LDS)
// Barrier groups: (dir,bgroup) -> 4 groups x 48 blocks (h-state is group-local).
__global__ __launch_bounds__(256) void lstm_persistent(
    const float* __restrict__ seq,               // [NB][NT][ND] f32
    const unsigned short* __restrict__ xbf,      // [NB][NT][ND] bf16 (optional)
    int use_xbf,
    const int* __restrict__ seq_len,             // [NB]
    const unsigned short* __restrict__ WT,       // [2][NG][KTOT] bf16
    const float* __restrict__ bias_fw,           // [NG]
    const float* __restrict__ bias_bw,           // [NG]
    unsigned short* __restrict__ hbufs,          // [3][2][NB][NH] bf16
    float* __restrict__ h_final,                 // [2][NB][NH] f32
    float* __restrict__ out,                     // [NB][NT][2*NH] f32
    unsigned int* __restrict__ barrier_cnts)     // 4 counters, 256B apart
{
    extern __shared__ char smem[];
    unsigned short* Wh = (unsigned short*)smem;              // [64][776] bf16 (h-part of W)
    unsigned short* A  = (unsigned short*)(smem + 64 * 776 * 2); // [32][776] staging
    float* gl = (float*)(smem + 64 * 776 * 2);               // overlay on A: [4][32][16]

    int bid = blockIdx.x;
    int hgroup = bid % 48;
    int bgroup = (bid / 48) & 1;
    int dir = bid / 96;
    int grp = bid / 48;                          // barrier group 0..3
    int b0 = bgroup * 32;
    int hbase = hgroup * 16;
    int tid = threadIdx.x;
    int lane = tid & 63;
    int wave = tid >> 6;                         // = gate index

    const unsigned short* Wd = WT + (size_t)dir * NG * KTOT;
    const float* bias = dir ? bias_bw : bias_fw;

    // ---- fill Wh (h-part rows of this block's 64 gate-cols) into LDS, once ----
    {
        int rl = tid >> 2;                       // local col 0..63 (gate*16 + hl)
        int gcol = (rl >> 4) * NH + hbase + (rl & 15);
        const unsigned short* src = Wd + (size_t)gcol * KTOT + ND;
        unsigned short* dstrow = Wh + rl * 776;
#pragma unroll
        for (int i = 0; i < 24; ++i) {
            int off = (tid & 3) * 8 + i * 32;
            *(bf16x8*)(dstrow + off) = *(const bf16x8*)(src + off);
        }
    }

    // ---- per-thread constants ----
    int srow = tid >> 3;                         // staging row 0..31
    int sb = b0 + srow;
    int Ls = seq_len[sb];
    int koff0 = (tid & 7) * 8;
    const float* xrow_f = seq + (size_t)sb * NT * ND;
    const unsigned short* xrow_b = use_xbf ? (xbf + (size_t)sb * NT * ND) : (const unsigned short*)0;

    int r0 = lane & 15;
    int q8 = (lane >> 4) * 8;
    int qq = lane >> 4;
    int col = wave * NH + hbase + r0;
    const unsigned short* BpX = Wd + (size_t)col * KTOT + q8;       // x-part B (global)
    const unsigned short* WhB = Wh + (size_t)(wave * 16 + r0) * 776 + q8; // h-part B (LDS)
    float bv = bias[col];

    // epilogue constants: thread owns (bl, hl) and (bl+16, hl)
    int ebl0 = tid >> 4;
    int ehl = tid & 15;
    int hidx = hbase + ehl;
    int Lb[2]; Lb[0] = seq_len[b0 + ebl0]; Lb[1] = seq_len[b0 + ebl0 + 16];
    float c_reg[2] = {0.f, 0.f};
    unsigned short h_reg[2] = {0, 0};

    unsigned int* cnt = barrier_cnts + grp * 64; // 256B apart

    for (int step = 0; step < NT; ++step) {
        const unsigned short* hin = hbufs + (size_t)(step % 3) * (2 * NB * NH) + (size_t)dir * NB * NH;
        unsigned short* hout      = hbufs + (size_t)((step + 1) % 3) * (2 * NB * NH) + (size_t)dir * NB * NH;

        int t_in = dir ? (Ls - 1 - step) : step;
        if (t_in < 0) t_in = 0;

        // ---- phase 1: stage x chunk (k 0..511) ----
        if (use_xbf) {
            const unsigned short* xr = xrow_b + (size_t)t_in * ND;
#pragma unroll
            for (int i = 0; i < 8; ++i) {
                int kl = koff0 + i * 64;
                *(bf16x8*)&A[srow * 776 + kl] = *(const bf16x8*)(xr + kl);
            }
        } else {
            const float* xr = xrow_f + (size_t)t_in * ND;
#pragma unroll
            for (int i = 0; i < 8; ++i) {
                int kl = koff0 + i * 64;
                float4 v0 = *(const float4*)(xr + kl);
                float4 v1 = *(const float4*)(xr + kl + 4);
                bf16x8 o;
                o[0] = (short)f2b(v0.x); o[1] = (short)f2b(v0.y);
                o[2] = (short)f2b(v0.z); o[3] = (short)f2b(v0.w);
                o[4] = (short)f2b(v1.x); o[5] = (short)f2b(v1.y);
                o[6] = (short)f2b(v1.z); o[7] = (short)f2b(v1.w);
                *(bf16x8*)&A[srow * 776 + kl] = o;
            }
        }
        __syncthreads();                          // (step0: also covers Wh fill)

        f32x4 acc0; acc0[0] = bv; acc0[1] = bv; acc0[2] = bv; acc0[3] = bv;
        f32x4 acc1 = acc0;
#pragma unroll
        for (int ks = 0; ks < 16; ++ks) {
            bf16x8 a0 = *(const bf16x8*)&A[r0 * 776 + ks * 32 + q8];
            bf16x8 a1 = *(const bf16x8*)&A[(r0 + 16) * 776 + ks * 32 + q8];
            bf16x8 bf = *(const bf16x8*)(BpX + ks * 32);
            acc0 = __builtin_amdgcn_mfma_f32_16x16x32_bf16(a0, bf, acc0, 0, 0, 0);
            acc1 = __builtin_amdgcn_mfma_f32_16x16x32_bf16(a1, bf, acc1, 0, 0, 0);
        }
        __syncthreads();                          // A consumed, restage with h

        // ---- phase 2: stage h (k 512..1279) ----
        {
            const unsigned short* hr = hin + (size_t)sb * NH;
#pragma unroll
            for (int i = 0; i < 12; ++i) {
                int kl = koff0 + i * 64;
                *(bf16x8*)&A[srow * 776 + kl] = *(const bf16x8*)(hr + kl);
            }
        }
        __syncthreads();
#pragma unroll
        for (int ks = 0; ks < 24; ++ks) {
            bf16x8 a0 = *(const bf16x8*)&A[r0 * 776 + ks * 32 + q8];
            bf16x8 a1 = *(const bf16x8*)&A[(r0 + 16) * 776 + ks * 32 + q8];
            bf16x8 bf = *(const bf16x8*)(WhB + ks * 32);
            acc0 = __builtin_amdgcn_mfma_f32_16x16x32_bf16(a0, bf, acc0, 0, 0, 0);
            acc1 = __builtin_amdgcn_mfma_f32_16x16x32_bf16(a1, bf, acc1, 0, 0, 0);
        }
        __syncthreads();                          // A done; gl overlay safe

        // C/D layout: col = lane&15, row = (lane>>4)*4 + reg
#pragma unroll
        for (int r = 0; r < 4; ++r) {
            gl[((size_t)wave * 32 + qq * 4 + r) * 16 + r0] = acc0[r];
            gl[((size_t)wave * 32 + 16 + qq * 4 + r) * 16 + r0] = acc1[r];
        }
        __syncthreads();

        // ---- epilogue: cell update, c/h in registers ----
#pragma unroll
        for (int it = 0; it < 2; ++it) {
            int bl = ebl0 + it * 16;
            int bb = b0 + bl;
            if (step < Lb[it]) {
                float gi = gl[(0 * 32 + bl) * 16 + ehl];
                float gj = gl[(1 * 32 + bl) * 16 + ehl];
                float gf = gl[(2 * 32 + bl) * 16 + ehl];
                float go = gl[(3 * 32 + bl) * 16 + ehl];
                float nc = c_reg[it] * sigmoidf_(gf + 1.f) + sigmoidf_(gi) * tanhf_(gj);
                float nh = tanhf_(nc) * sigmoidf_(go);
                c_reg[it] = nc;
                h_reg[it] = f2b(nh);
                if (step == Lb[it] - 1)
                    h_final[((size_t)dir * NB + bb) * NH + hidx] = nh;
                int t_out = dir ? (Lb[it] - 1 - step) : step;
                out[((size_t)bb * NT + t_out) * (2 * NH) + dir * NH + hidx] = nh;
            }
            hout[(size_t)bb * NH + hidx] = h_reg[it];
        }

        // ---- group barrier (48 blocks sharing this dir+bgroup's h state) ----
        __syncthreads();
        if (tid == 0) {
            __hip_atomic_fetch_add(cnt, 1u, __ATOMIC_RELEASE, __HIP_MEMORY_SCOPE_AGENT);
            unsigned int tgt = 48u * (unsigned)(step + 1);
            while (__hip_atomic_load(cnt, __ATOMIC_RELAXED, __HIP_MEMORY_SCOPE_AGENT) < tgt)
                __builtin_amdgcn_s_sleep(2);
            (void)__hip_atomic_load(cnt, __ATOMIC_ACQUIRE, __HIP_MEMORY_SCOPE_AGENT);
        }
        __syncthreads();
    }
}

// ---------------- final hidden state (f32) -> d_out tail ----------------
__global__ __launch_bounds__(256) void write_state(const float* __restrict__ h_final,
                                                   float* __restrict__ out_state) {
    int i = blockIdx.x * 256 + threadIdx.x;      // over 2*NB*NH
    if (i < 2 * NB * NH) {
        int dir = i / (NB * NH);
        int rem = i - dir * (NB * NH);
        int b = rem / NH, h = rem - (rem / NH) * NH;
        out_state[(size_t)b * (2 * NH) + dir * NH + h] = h_final[i];
    }
}

extern "C" void kernel_launch(void* const* d_in, const int* in_sizes, int n_in,
                              void* d_out, int out_size, void* d_ws, size_t ws_size,
                              hipStream_t stream) {
    const float* seq   = (const float*)d_in[0];
    const int* seq_len = (const int*)d_in[1];
    const float* W_fw  = (const float*)d_in[2];
    const float* b_fw  = (const float*)d_in[3];
    const float* W_bw  = (const float*)d_in[4];
    const float* b_bw  = (const float*)d_in[5];
    float* out = (float*)d_out;

    char* ws = (char*)d_ws;
    size_t off = 0;
    unsigned short* WT = (unsigned short*)(ws + off);  off += (size_t)2 * NG * KTOT * 2;   // 15,728,640
    unsigned short* hbufs = (unsigned short*)(ws + off);
    size_t hbuf_bytes = (size_t)3 * 2 * NB * NH * 2;   off += hbuf_bytes;                  // 589,824
    float* h_final = (float*)(ws + off);
    size_t hf_bytes = (size_t)2 * NB * NH * 4;         off += hf_bytes;                    // 393,216
    unsigned int* barrier_cnts = (unsigned int*)(ws + off);
    size_t bar_bytes = 1024;                           off += bar_bytes;
    unsigned short* xbf = (unsigned short*)(ws + off);
    size_t xbf_bytes = (size_t)NB * NT * ND * 2;       // 33,554,432
    int use_xbf = (ws_size >= off + xbf_bytes) ? 1 : 0;

    // zero outputs (masked positions must be exactly 0), h buffers, barrier
    hipMemsetAsync(out, 0, (size_t)NB * NT * 2 * NH * sizeof(float), stream);
    hipMemsetAsync(hbufs, 0, hbuf_bytes + hf_bytes + bar_bytes, stream);

    transpose_w<<<(KTOT / 64) * (NG / 64), 256, 0, stream>>>(W_fw, WT);
    transpose_w<<<(KTOT / 64) * (NG / 64), 256, 0, stream>>>(W_bw, WT + (size_t)NG * KTOT);
    if (use_xbf) {
        int n8 = NB * NT * ND / 8;
        convert_x<<<(n8 + 255) / 256, 256, 0, stream>>>(seq, xbf, n8);
    }

    size_t smem_bytes = (size_t)64 * 776 * 2 + (size_t)32 * 776 * 2;   // 148,992
    lstm_persistent<<<192, 256, smem_bytes, stream>>>(
        seq, xbf, use_xbf, seq_len, WT, b_fw, b_bw,
        hbufs, h_final, out, barrier_cnts);

    write_state<<<(2 * NB * NH + 255) / 256, 256, 0, stream>>>(
        h_final, out + (size_t)NB * NT * 2 * NH);
}